// Round 3
// baseline (586.591 us; speedup 1.0000x reference)
//
#include <hip/hip_runtime.h>
#include <hip/hip_bf16.h>

// MiniTransformer: B=131072, T=8, D=32, H=64, V=27
// R3: inputs f32 (confirmed: bf16 reinterpretation NaN'd in R1), output f32
// (confirmed: bf16 stores gave the odd-index-aliasing 0.68 error in R2).
// 1 thread per (b,t) row. Weight reads use compile-time-uniform indices ->
// scalar s_load, SGPR operand in v_fmac. K/V shared across t via padded LDS.

namespace {
constexpr int BTOT = 131072;
constexpr int T = 8;
constexpr int D = 32;
constexpr int H = 64;
constexpr int V = 27;
constexpr float EPS = 1e-5f;

constexpr int BPB  = 24;        // batch elements per block
constexpr int NTHR = BPB * T;   // 192 threads
constexpr int PB   = 260;       // per-b LDS stride (floats); 260%32=4 -> spreads banks across b
} // namespace

__global__ __launch_bounds__(NTHR) void mini_transformer_kernel(
    const int* __restrict__ tokens,
    const float* __restrict__ tokE,
    const float* __restrict__ posE,
    const float* __restrict__ Wq,
    const float* __restrict__ Wk,
    const float* __restrict__ Wv,
    const float* __restrict__ W1,
    const float* __restrict__ W2,
    const float* __restrict__ Wo,
    float* __restrict__ out) {
  __shared__ float Ks[BPB * PB];
  __shared__ float Vs[BPB * PB];

  const int tid = threadIdx.x;
  const int bl  = tid >> 3;   // local batch index within block
  const int t   = tid & 7;    // sequence position
  const long long b = (long long)blockIdx.x * BPB + bl;
  const bool active = b < BTOT;

  float x[D];   // embedding row (residual 1)
  float q[D];   // query row

  if (active) {
    const int tok = tokens[b * T + t];
    const float4* xe = (const float4*)(tokE + tok * D);
    const float4* pe = (const float4*)(posE + t * D);
#pragma unroll
    for (int g = 0; g < D / 4; ++g) {
      const float4 a = xe[g], c = pe[g];
      x[4 * g + 0] = a.x + c.x;
      x[4 * g + 1] = a.y + c.y;
      x[4 * g + 2] = a.z + c.z;
      x[4 * g + 3] = a.w + c.w;
    }
    // Q/K/V projections; weights are uniform -> scalar loads.
#pragma unroll
    for (int d = 0; d < D; ++d) {
      float aq = 0.f, ak = 0.f, av = 0.f;
#pragma unroll
      for (int k = 0; k < D; ++k) {
        const float xv = x[k];
        aq = fmaf(xv, Wq[k * D + d], aq);
        ak = fmaf(xv, Wk[k * D + d], ak);
        av = fmaf(xv, Wv[k * D + d], av);
      }
      q[d] = aq;
      Ks[bl * PB + t * D + d] = ak;
      Vs[bl * PB + t * D + d] = av;
    }
  }
  __syncthreads();

  if (active) {
    // scores[t][s] = Q . K_s  (no 1/sqrt(d), per reference)
    float sc[T];
#pragma unroll
    for (int s = 0; s < T; ++s) {
      float a = 0.f;
      const float4* kk = (const float4*)&Ks[bl * PB + s * D];
#pragma unroll
      for (int g = 0; g < D / 4; ++g) {
        const float4 kv = kk[g];
        a = fmaf(q[4 * g + 0], kv.x, a);
        a = fmaf(q[4 * g + 1], kv.y, a);
        a = fmaf(q[4 * g + 2], kv.z, a);
        a = fmaf(q[4 * g + 3], kv.w, a);
      }
      sc[s] = a;
    }
    // causal softmax over s<=t
    float mx = -INFINITY;
#pragma unroll
    for (int s = 0; s < T; ++s) mx = fmaxf(mx, (s <= t) ? sc[s] : -INFINITY);
    float p[T];
    float den = 0.f;
#pragma unroll
    for (int s = 0; s < T; ++s) {
      p[s] = (s <= t) ? __expf(sc[s] - mx) : 0.f;
      den += p[s];
    }
    const float inv = 1.f / den;

    // attn @ V, + residual x
    float o[D];
#pragma unroll
    for (int g = 0; g < D / 4; ++g) {
      float ax = 0.f, ay = 0.f, az = 0.f, aw = 0.f;
#pragma unroll
      for (int s = 0; s < T; ++s) {
        const float4 vv = *(const float4*)&Vs[bl * PB + s * D + 4 * g];
        ax = fmaf(p[s], vv.x, ax);
        ay = fmaf(p[s], vv.y, ay);
        az = fmaf(p[s], vv.z, az);
        aw = fmaf(p[s], vv.w, aw);
      }
      o[4 * g + 0] = ax * inv + x[4 * g + 0];
      o[4 * g + 1] = ay * inv + x[4 * g + 1];
      o[4 * g + 2] = az * inv + x[4 * g + 2];
      o[4 * g + 3] = aw * inv + x[4 * g + 3];
    }

    // LayerNorm 1 (row-private, no cross-lane)
    {
      float s1 = 0.f;
#pragma unroll
      for (int d = 0; d < D; ++d) s1 += o[d];
      const float mean = s1 * (1.f / D);
      float s2 = 0.f;
#pragma unroll
      for (int d = 0; d < D; ++d) { const float c = o[d] - mean; s2 = fmaf(c, c, s2); }
      const float r = rsqrtf(s2 * (1.f / D) + EPS);
#pragma unroll
      for (int d = 0; d < D; ++d) o[d] = (o[d] - mean) * r;
    }

    // MLP: relu(o @ W1) @ W2, h chunked by 16 to bound registers
    float y[D];
#pragma unroll
    for (int d = 0; d < D; ++d) y[d] = 0.f;
#pragma unroll
    for (int jc = 0; jc < H / 16; ++jc) {
      float hh[16];
#pragma unroll
      for (int jj = 0; jj < 16; ++jj) {
        const int j = jc * 16 + jj;
        float a = 0.f;
#pragma unroll
        for (int d = 0; d < D; ++d) a = fmaf(o[d], W1[d * H + j], a);
        hh[jj] = fmaxf(a, 0.f);
      }
#pragma unroll
      for (int jj = 0; jj < 16; ++jj) {
        const int j = jc * 16 + jj;
#pragma unroll
        for (int d = 0; d < D; ++d) y[d] = fmaf(hh[jj], W2[j * D + d], y[d]);
      }
    }

    // residual + LayerNorm 2
#pragma unroll
    for (int d = 0; d < D; ++d) y[d] += o[d];
    {
      float s1 = 0.f;
#pragma unroll
      for (int d = 0; d < D; ++d) s1 += y[d];
      const float mean = s1 * (1.f / D);
      float s2 = 0.f;
#pragma unroll
      for (int d = 0; d < D; ++d) { const float c = y[d] - mean; s2 = fmaf(c, c, s2); }
      const float r = rsqrtf(s2 * (1.f / D) + EPS);
#pragma unroll
      for (int d = 0; d < D; ++d) y[d] = (y[d] - mean) * r;
    }

    // output projection [D]->[V], f32 store
    float* op = out + (long long)(b * T + t) * V;
#pragma unroll
    for (int v = 0; v < V; ++v) {
      float a = 0.f;
#pragma unroll
      for (int d = 0; d < D; ++d) a = fmaf(y[d], Wo[d * V + v], a);
      op[v] = a;
    }
  }
}

extern "C" void kernel_launch(void* const* d_in, const int* in_sizes, int n_in,
                              void* d_out, int out_size, void* d_ws, size_t ws_size,
                              hipStream_t stream) {
  const int*   tokens  = (const int*)d_in[0];
  const float* tok_emb = (const float*)d_in[1];
  const float* pos_emb = (const float*)d_in[2];
  const float* Wq      = (const float*)d_in[3];
  const float* Wk      = (const float*)d_in[4];
  const float* Wv      = (const float*)d_in[5];
  const float* W1      = (const float*)d_in[6];
  const float* W2      = (const float*)d_in[7];
  const float* Wout    = (const float*)d_in[8];

  const int nblocks = (BTOT + BPB - 1) / BPB;
  hipLaunchKernelGGL(mini_transformer_kernel, dim3(nblocks), dim3(NTHR), 0, stream,
                     tokens, tok_emb, pos_emb, Wq, Wk, Wv, W1, W2, Wout,
                     (float*)d_out);
}

// Round 4
// 399.424 us; speedup vs baseline: 1.4686x; 1.4686x over previous
//
#include <hip/hip_runtime.h>

// MiniTransformer: B=131072, T=8, D=32, H=64, V=27  (all f32, out f32)
// R4: table precompute. x/Q/K/V rows depend only on (t,token) -> 216 rows.
//   ws: X[216][32], V[216][32], SC[t][tok_t][s][tok_s] (46656) precomputed by
//   two tiny kernels. Main kernel: LDS-free (occupancy was LDS-capped at 24%,
//   and the old K/V LDS writes had 8-way bank conflicts: t-stride 32 == bank
//   count). Per-row work drops 8544 -> ~5300 MACs (MLP dominates).

namespace {
constexpr int BTOT = 131072;
constexpr int T = 8;
constexpr int D = 32;
constexpr int H = 64;
constexpr int V = 27;
constexpr int NTOK = 27;
constexpr int NROW = T * NTOK;      // 216
constexpr float EPS = 1e-5f;

// ws layout (float offsets)
constexpr int WS_X  = 0;            // 216*32 = 6912
constexpr int WS_Q  = 6912;
constexpr int WS_K  = 13824;
constexpr int WS_V  = 20736;
constexpr int WS_SC = 27648;        // 216*216 = 46656
constexpr int NSC   = NROW * NROW;
} // namespace

// ---- kernel A: X/Q/K/V row tables (216 rows, one block) ----
__global__ __launch_bounds__(256) void build_rows_kernel(
    const float* __restrict__ tokE, const float* __restrict__ posE,
    const float* __restrict__ Wq, const float* __restrict__ Wk,
    const float* __restrict__ Wv, float* __restrict__ ws) {
  const int i = threadIdx.x;
  if (i >= NROW) return;
  const int t = i / NTOK, tok = i % NTOK;
  float x[D];
#pragma unroll
  for (int d = 0; d < D; ++d) x[d] = tokE[tok * D + d] + posE[t * D + d];
  float* X = ws + WS_X + i * D;
  float* Q = ws + WS_Q + i * D;
  float* K = ws + WS_K + i * D;
  float* Vr = ws + WS_V + i * D;
#pragma unroll
  for (int d = 0; d < D; ++d) X[d] = x[d];
#pragma unroll
  for (int d = 0; d < D; ++d) {
    float aq = 0.f, ak = 0.f, av = 0.f;
#pragma unroll
    for (int k = 0; k < D; ++k) {
      const float xv = x[k];
      aq = fmaf(xv, Wq[k * D + d], aq);
      ak = fmaf(xv, Wk[k * D + d], ak);
      av = fmaf(xv, Wv[k * D + d], av);
    }
    Q[d] = aq; K[d] = ak; Vr[d] = av;
  }
}

// ---- kernel B: score table SC[((t*27+tokt)*8+s)*27+toks] = Q_row . K_row ----
__global__ __launch_bounds__(256) void build_sc_kernel(float* __restrict__ ws) {
  const int i = blockIdx.x * 256 + threadIdx.x;
  if (i >= NSC) return;
  const int qrow = i / NROW;        // t*27 + tok_t
  const int j    = i - qrow * NROW; // s*27 + tok_s
  const float4* q = (const float4*)(ws + WS_Q + qrow * D);
  const float4* k = (const float4*)(ws + WS_K + j * D);
  float a = 0.f;
#pragma unroll
  for (int g = 0; g < D / 4; ++g) {
    const float4 qa = q[g], ka = k[g];
    a = fmaf(qa.x, ka.x, a);
    a = fmaf(qa.y, ka.y, a);
    a = fmaf(qa.z, ka.z, a);
    a = fmaf(qa.w, ka.w, a);
  }
  ws[WS_SC + i] = a;
}

// ---- kernel C: main. 1 thread per (b,t) row, no LDS. ----
__global__ __launch_bounds__(256) void mini_transformer_kernel(
    const int* __restrict__ tokens,
    const float* __restrict__ ws,
    const float* __restrict__ W1,
    const float* __restrict__ W2,
    const float* __restrict__ Wo,
    float* __restrict__ out) {
  const int r = blockIdx.x * 256 + threadIdx.x;  // global row, grid covers exactly BTOT*T
  const int b = r >> 3;
  const int t = r & 7;

  // this row's token (coalesced: tokens[r]) + whole token row (32B broadcast per b)
  const int tok_t = tokens[r];
  const int4 ta = *(const int4*)(tokens + b * T);
  const int4 tb = *(const int4*)(tokens + b * T + 4);
  int toks[T];
  toks[0] = ta.x; toks[1] = ta.y; toks[2] = ta.z; toks[3] = ta.w;
  toks[4] = tb.x; toks[5] = tb.y; toks[6] = tb.z; toks[7] = tb.w;

  // scores from table (only s<=t live)
  const float* SC = ws + WS_SC + (t * NTOK + tok_t) * NROW;
  float sc[T];
#pragma unroll
  for (int s = 0; s < T; ++s)
    sc[s] = (s <= t) ? SC[s * NTOK + toks[s]] : -INFINITY;

  float mx = -INFINITY;
#pragma unroll
  for (int s = 0; s < T; ++s) mx = fmaxf(mx, sc[s]);
  float p[T];
  float den = 0.f;
#pragma unroll
  for (int s = 0; s < T; ++s) {
    p[s] = (s <= t) ? __expf(sc[s] - mx) : 0.f;
    den += p[s];
  }
  const float inv = 1.f / den;

  // o = (attn @ V) * inv + x   (V rows gathered from L1-resident table)
  float o[D];
#pragma unroll
  for (int d = 0; d < D; ++d) o[d] = 0.f;
#pragma unroll
  for (int s = 0; s < T; ++s) {
    if (s <= t) {
      const float4* vr = (const float4*)(ws + WS_V + (s * NTOK + toks[s]) * D);
      const float ps = p[s];
#pragma unroll
      for (int g = 0; g < D / 4; ++g) {
        const float4 v4 = vr[g];
        o[4 * g + 0] = fmaf(ps, v4.x, o[4 * g + 0]);
        o[4 * g + 1] = fmaf(ps, v4.y, o[4 * g + 1]);
        o[4 * g + 2] = fmaf(ps, v4.z, o[4 * g + 2]);
        o[4 * g + 3] = fmaf(ps, v4.w, o[4 * g + 3]);
      }
    }
  }
  {
    const float4* xr = (const float4*)(ws + WS_X + (t * NTOK + tok_t) * D);
#pragma unroll
    for (int g = 0; g < D / 4; ++g) {
      const float4 x4 = xr[g];
      o[4 * g + 0] = fmaf(o[4 * g + 0], inv, x4.x);
      o[4 * g + 1] = fmaf(o[4 * g + 1], inv, x4.y);
      o[4 * g + 2] = fmaf(o[4 * g + 2], inv, x4.z);
      o[4 * g + 3] = fmaf(o[4 * g + 3], inv, x4.w);
    }
  }

  // LayerNorm 1
  {
    float s1 = 0.f;
#pragma unroll
    for (int d = 0; d < D; ++d) s1 += o[d];
    const float mean = s1 * (1.f / D);
    float s2 = 0.f;
#pragma unroll
    for (int d = 0; d < D; ++d) { const float c = o[d] - mean; s2 = fmaf(c, c, s2); }
    const float rr = rsqrtf(s2 * (1.f / D) + EPS);
#pragma unroll
    for (int d = 0; d < D; ++d) o[d] = (o[d] - mean) * rr;
  }

  // MLP: relu(o @ W1) @ W2 (weights via uniform s_load), h chunked by 16
  float y[D];
#pragma unroll
  for (int d = 0; d < D; ++d) y[d] = 0.f;
#pragma unroll
  for (int jc = 0; jc < H / 16; ++jc) {
    float hh[16];
#pragma unroll
    for (int jj = 0; jj < 16; ++jj) {
      const int j = jc * 16 + jj;
      float a = 0.f;
#pragma unroll
      for (int d = 0; d < D; ++d) a = fmaf(o[d], W1[d * H + j], a);
      hh[jj] = fmaxf(a, 0.f);
    }
#pragma unroll
    for (int jj = 0; jj < 16; ++jj) {
      const int j = jc * 16 + jj;
#pragma unroll
      for (int d = 0; d < D; ++d) y[d] = fmaf(hh[jj], W2[j * D + d], y[d]);
    }
  }

  // residual + LayerNorm 2
#pragma unroll
  for (int d = 0; d < D; ++d) y[d] += o[d];
  {
    float s1 = 0.f;
#pragma unroll
    for (int d = 0; d < D; ++d) s1 += y[d];
    const float mean = s1 * (1.f / D);
    float s2 = 0.f;
#pragma unroll
    for (int d = 0; d < D; ++d) { const float c = y[d] - mean; s2 = fmaf(c, c, s2); }
    const float rr = rsqrtf(s2 * (1.f / D) + EPS);
#pragma unroll
    for (int d = 0; d < D; ++d) y[d] = (y[d] - mean) * rr;
  }

  // output projection [D]->[V]
  float* op = out + (long long)r * V;
#pragma unroll
  for (int v = 0; v < V; ++v) {
    float a = 0.f;
#pragma unroll
    for (int d = 0; d < D; ++d) a = fmaf(y[d], Wo[d * V + v], a);
    op[v] = a;
  }
}

extern "C" void kernel_launch(void* const* d_in, const int* in_sizes, int n_in,
                              void* d_out, int out_size, void* d_ws, size_t ws_size,
                              hipStream_t stream) {
  const int*   tokens  = (const int*)d_in[0];
  const float* tok_emb = (const float*)d_in[1];
  const float* pos_emb = (const float*)d_in[2];
  const float* Wq      = (const float*)d_in[3];
  const float* Wk      = (const float*)d_in[4];
  const float* Wv      = (const float*)d_in[5];
  const float* W1      = (const float*)d_in[6];
  const float* W2      = (const float*)d_in[7];
  const float* Wout    = (const float*)d_in[8];
  float* ws = (float*)d_ws;

  hipLaunchKernelGGL(build_rows_kernel, dim3(1), dim3(256), 0, stream,
                     tok_emb, pos_emb, Wq, Wk, Wv, ws);
  hipLaunchKernelGGL(build_sc_kernel, dim3((NSC + 255) / 256), dim3(256), 0, stream, ws);

  const int nblocks = (BTOT * T) / 256;  // 4096, exact
  hipLaunchKernelGGL(mini_transformer_kernel, dim3(nblocks), dim3(256), 0, stream,
                     tokens, ws, W1, W2, Wout, (float*)d_out);
}